// Round 4
// baseline (2201.467 us; speedup 1.0000x reference)
//
#include <hip/hip_runtime.h>

typedef _Float16 f16;
typedef _Float16 f16x4 __attribute__((ext_vector_type(4)));
typedef _Float16 f16x8 __attribute__((ext_vector_type(8)));
typedef float f32x16 __attribute__((ext_vector_type(16)));

#define MFMA16(a, b, c) __builtin_amdgcn_mfma_f32_32x32x16_f16((a), (b), (c), 0, 0, 0)

constexpr int B_ = 4, H_ = 16, S_ = 2048, D_ = 64;
constexpr int QB = 128;          // q rows per workgroup (4 waves x 32)
constexpr int WQ = 32;           // q rows per wave
constexpr int KB = 64;           // k/v rows per LDS tile
constexpr int NKT = S_ / KB;     // 32
constexpr size_t OUT0 = (size_t)B_ * H_ * S_ * D_;  // offset of attn in d_out

// XOR-swizzled byte offset in a row-major [rows][64] f16 tile (128B rows).
// Fixes the 32-way bank conflict of per-row ds_read_b128 at 128B stride.
__device__ __forceinline__ int swzb(int row, int col /*f16 units*/) {
  int byte = (row << 7) + (col << 1);
  return byte ^ ((row & 7) << 4);
}

__global__ __launch_bounds__(256) void attn_fused(
    const float* __restrict__ qg_, const float* __restrict__ kg_,
    const float* __restrict__ vg_, const int* __restrict__ mg_,
    float* __restrict__ out) {
  __shared__ f16 Kl[KB * D_];      // 8 KB, K tile  [t][d]
  __shared__ f16 Vt[D_ * KB];      // 8 KB, V tile transposed [d][t]
  __shared__ f16 Pl[4 * WQ * KB];  // 16 KB, per-wave P tile [q][t]

  const int tid = threadIdx.x;
  const int lane = tid & 63;
  const int wid = tid >> 6;
  const int ln = lane & 31;
  const int hi = lane >> 5;

  const int bh = blockIdx.y;
  const int b = bh >> 4;
  const int qb = blockIdx.x * QB + wid * WQ;  // wave's first q row

  const float* qg = qg_ + (size_t)bh * S_ * D_;
  const float* kg = kg_ + (size_t)bh * S_ * D_;
  const float* vg = vg_ + (size_t)bh * S_ * D_;
  const int* mg = mg_ + (size_t)b * S_ * S_;
  float* outp = out + (size_t)bh * S_ * D_;
  float* attnp = out + OUT0 + (size_t)bh * S_ * S_;

  char* KlB = (char*)Kl;
  char* VtB = (char*)Vt;
  char* PlB = (char*)Pl + wid * (WQ * KB * 2);

  // ---- hoist Q fragments (x 1/8 folded in), row = qb + ln ----
  f16x8 qf[4];
  {
    const float* qrow = qg + (size_t)(qb + ln) * D_;
#pragma unroll
    for (int s = 0; s < 4; ++s) {
      const int d0 = s * 16 + hi * 8;
      float4 a = *(const float4*)(qrow + d0);
      float4 c = *(const float4*)(qrow + d0 + 4);
      f16x8 t;
      t[0] = (f16)(a.x * 0.125f); t[1] = (f16)(a.y * 0.125f);
      t[2] = (f16)(a.z * 0.125f); t[3] = (f16)(a.w * 0.125f);
      t[4] = (f16)(c.x * 0.125f); t[5] = (f16)(c.y * 0.125f);
      t[6] = (f16)(c.z * 0.125f); t[7] = (f16)(c.w * 0.125f);
      qf[s] = t;
    }
  }

  float rsum[16];
#pragma unroll
  for (int r = 0; r < 16; ++r) rsum[r] = 0.0f;

  // ---- pass 1: masked exp row-sums (scores discarded) ----
  for (int kt = 0; kt < NKT; ++kt) {
    __syncthreads();
#pragma unroll
    for (int rep = 0; rep < 4; ++rep) {
      const int idx = (rep * 256 + tid) * 4;
      const int row = idx >> 6, col = idx & 63;
      float4 x = *(const float4*)(kg + (size_t)(kt * KB + row) * D_ + col);
      f16x4 hx = {(f16)x.x, (f16)x.y, (f16)x.z, (f16)x.w};
      *(f16x4*)(KlB + swzb(row, col)) = hx;
    }
    __syncthreads();
#pragma unroll
    for (int sub = 0; sub < 2; ++sub) {
      f32x16 sacc;
#pragma unroll
      for (int i = 0; i < 16; ++i) sacc[i] = 0.0f;
#pragma unroll
      for (int s = 0; s < 4; ++s) {
        f16x8 kf = *(const f16x8*)(KlB + swzb(sub * 32 + ln, s * 16 + hi * 8));
        sacc = MFMA16(qf[s], kf, sacc);
      }
      const int t0 = kt * KB + sub * 32;
      const int* mrow = mg + (size_t)(qb + 4 * hi) * S_ + t0 + ln;
#pragma unroll
      for (int r = 0; r < 16; ++r) {
        const int qoff = (r & 3) + 8 * (r >> 2);
        const int m = mrow[(size_t)qoff * S_];
        rsum[r] += (m != 0) ? __expf(sacc[r]) : 0.0f;
      }
    }
  }

  // ---- reduce row sums over the 32 t-lanes, invert ----
  float rinv[16];
#pragma unroll
  for (int r = 0; r < 16; ++r) {
    float s = rsum[r];
    s += __shfl_xor(s, 16);
    s += __shfl_xor(s, 8);
    s += __shfl_xor(s, 4);
    s += __shfl_xor(s, 2);
    s += __shfl_xor(s, 1);
    rinv[r] = 1.0f / s;
  }

  f32x16 oacc0, oacc1;
#pragma unroll
  for (int i = 0; i < 16; ++i) { oacc0[i] = 0.0f; oacc1[i] = 0.0f; }

  // ---- pass 2: recompute scores, write attn, accumulate AV ----
  for (int kt = 0; kt < NKT; ++kt) {
    __syncthreads();
#pragma unroll
    for (int rep = 0; rep < 4; ++rep) {
      const int idx = (rep * 256 + tid) * 4;
      const int row = idx >> 6, col = idx & 63;
      float4 x = *(const float4*)(kg + (size_t)(kt * KB + row) * D_ + col);
      f16x4 hx = {(f16)x.x, (f16)x.y, (f16)x.z, (f16)x.w};
      *(f16x4*)(KlB + swzb(row, col)) = hx;
      float4 y = *(const float4*)(vg + (size_t)(kt * KB + row) * D_ + col);
      *(f16*)(VtB + swzb(col + 0, row)) = (f16)y.x;
      *(f16*)(VtB + swzb(col + 1, row)) = (f16)y.y;
      *(f16*)(VtB + swzb(col + 2, row)) = (f16)y.z;
      *(f16*)(VtB + swzb(col + 3, row)) = (f16)y.w;
    }
    __syncthreads();
#pragma unroll
    for (int sub = 0; sub < 2; ++sub) {
      f32x16 sacc;
#pragma unroll
      for (int i = 0; i < 16; ++i) sacc[i] = 0.0f;
#pragma unroll
      for (int s = 0; s < 4; ++s) {
        f16x8 kf = *(const f16x8*)(KlB + swzb(sub * 32 + ln, s * 16 + hi * 8));
        sacc = MFMA16(qf[s], kf, sacc);
      }
      const int t0 = kt * KB + sub * 32;
      const int* mrow = mg + (size_t)(qb + 4 * hi) * S_ + t0 + ln;
      float* arow = attnp + (size_t)(qb + 4 * hi) * S_ + t0 + ln;
#pragma unroll
      for (int r = 0; r < 16; ++r) {
        const int qoff = (r & 3) + 8 * (r >> 2);
        const int m = mrow[(size_t)qoff * S_];
        float p = (m != 0) ? __expf(sacc[r]) * rinv[r] : 0.0f;
        arow[(size_t)qoff * S_] = p;  // f32 attn output, coalesced along t
        *(f16*)(PlB + swzb(qoff + 4 * hi, sub * 32 + ln)) = (f16)p;
      }
    }
    // AV: A = P (per-wave LDS), B = V^T; same-wave LDS dep -> lgkmcnt only
#pragma unroll
    for (int ts = 0; ts < 4; ++ts) {
      f16x8 pa = *(const f16x8*)(PlB + swzb(ln, ts * 16 + hi * 8));
      f16x8 vb0 = *(const f16x8*)(VtB + swzb(ln, ts * 16 + hi * 8));
      f16x8 vb1 = *(const f16x8*)(VtB + swzb(32 + ln, ts * 16 + hi * 8));
      oacc0 = MFMA16(pa, vb0, oacc0);
      oacc1 = MFMA16(pa, vb1, oacc1);
    }
  }

  // ---- epilogue: output = AV + v (residual) ----
#pragma unroll
  for (int r = 0; r < 16; ++r) {
    const int qoff = (r & 3) + 8 * (r >> 2);
    const size_t o = (size_t)(qb + qoff + 4 * hi) * D_ + ln;
    outp[o] = oacc0[r] + vg[o];
    outp[o + 32] = oacc1[r] + vg[o + 32];
  }
}

extern "C" void kernel_launch(void* const* d_in, const int* in_sizes, int n_in,
                              void* d_out, int out_size, void* d_ws, size_t ws_size,
                              hipStream_t stream) {
  (void)in_sizes; (void)n_in; (void)out_size; (void)d_ws; (void)ws_size;
  const float* q = (const float*)d_in[0];
  const float* k = (const float*)d_in[1];
  const float* v = (const float*)d_in[2];
  const int* mask = (const int*)d_in[3];
  float* out = (float*)d_out;
  dim3 grid(S_ / QB, B_ * H_);
  attn_fused<<<grid, dim3(256), 0, stream>>>(q, k, v, mask, out);
}

// Round 5
// 2153.966 us; speedup vs baseline: 1.0221x; 1.0221x over previous
//
#include <hip/hip_runtime.h>

typedef _Float16 f16;
typedef _Float16 f16x4 __attribute__((ext_vector_type(4)));
typedef _Float16 f16x8 __attribute__((ext_vector_type(8)));
typedef float f32x16 __attribute__((ext_vector_type(16)));

#define MFMA16(a, b, c) __builtin_amdgcn_mfma_f32_32x32x16_f16((a), (b), (c), 0, 0, 0)

constexpr int B_ = 4, H_ = 16, S_ = 2048, D_ = 64, BH = 64;
constexpr int QB = 128;            // q rows per WG (4 waves x 32)
constexpr int WQ = 32;             // q rows per wave
constexpr int KB = 64;             // k/v rows per LDS tile
constexpr int TS = 512;            // t-range per WG for K1/K2
constexpr int NSPLIT = S_ / TS;    // 4
constexpr int NKT_W = TS / KB;     // 8
constexpr int NKT = S_ / KB;       // 32
constexpr size_t OUT0 = (size_t)B_ * H_ * S_ * D_;

// XOR-swizzled byte offset in a row-major [rows][64] f16 tile (128B rows).
__device__ __forceinline__ int swzb(int row, int col /*f16 units*/) {
  int byte = (row << 7) + (col << 1);
  return byte ^ ((row & 7) << 4);
}

// 256-thread cooperative: K-tile (64x64 f32) -> 4 float4 regs/thread
__device__ __forceinline__ void kload256(const float* g, int kt, int tid, float4 kr[4]) {
#pragma unroll
  for (int rep = 0; rep < 4; ++rep) {
    int idx = (rep * 256 + tid) * 4;
    kr[rep] = *(const float4*)(g + (size_t)(kt * KB + (idx >> 6)) * D_ + (idx & 63));
  }
}
__device__ __forceinline__ void kwrite256(char* KlB, int tid, const float4 kr[4]) {
#pragma unroll
  for (int rep = 0; rep < 4; ++rep) {
    int idx = (rep * 256 + tid) * 4;
    f16x4 hx = {(f16)kr[rep].x, (f16)kr[rep].y, (f16)kr[rep].z, (f16)kr[rep].w};
    *(f16x4*)(KlB + swzb(idx >> 6, idx & 63)) = hx;
  }
}
__device__ __forceinline__ void vwrite256(char* VtB, int tid, const float4 vr[4]) {
#pragma unroll
  for (int rep = 0; rep < 4; ++rep) {
    int idx = (rep * 256 + tid) * 4;
    int row = idx >> 6, col = idx & 63;
    *(f16*)(VtB + swzb(col + 0, row)) = (f16)vr[rep].x;
    *(f16*)(VtB + swzb(col + 1, row)) = (f16)vr[rep].y;
    *(f16*)(VtB + swzb(col + 2, row)) = (f16)vr[rep].z;
    *(f16*)(VtB + swzb(col + 3, row)) = (f16)vr[rep].w;
  }
}

__device__ __forceinline__ void load_qf(const float* qg, int qrow, int hi, f16x8 qf[4]) {
  const float* qr = qg + (size_t)qrow * D_;
#pragma unroll
  for (int s = 0; s < 4; ++s) {
    const int d0 = s * 16 + hi * 8;
    float4 a = *(const float4*)(qr + d0);
    float4 c = *(const float4*)(qr + d0 + 4);
    f16x8 t;
    t[0] = (f16)(a.x * 0.125f); t[1] = (f16)(a.y * 0.125f);
    t[2] = (f16)(a.z * 0.125f); t[3] = (f16)(a.w * 0.125f);
    t[4] = (f16)(c.x * 0.125f); t[5] = (f16)(c.y * 0.125f);
    t[6] = (f16)(c.z * 0.125f); t[7] = (f16)(c.w * 0.125f);
    qf[s] = t;
  }
}

__device__ __forceinline__ f32x16 qk8(const char* KlB, const f16x8 qf[4], int sub, int ln, int hi) {
  f32x16 s;
#pragma unroll
  for (int i = 0; i < 16; ++i) s[i] = 0.0f;
#pragma unroll
  for (int t = 0; t < 4; ++t) {
    f16x8 kf = *(const f16x8*)(KlB + swzb(sub * 32 + ln, t * 16 + hi * 8));
    s = MFMA16(qf[t], kf, s);
  }
  return s;
}

// ---------------- K0: zero the rsum workspace ----------------
__global__ void zero_ws(float* __restrict__ p, int n) {
  int i = blockIdx.x * blockDim.x + threadIdx.x;
  if (i < n) p[i] = 0.0f;
}

// ---------------- K1: masked exp row-sums (t-split, atomic) ----------------
__global__ __launch_bounds__(256, 4) void attn_rsum(
    const float* __restrict__ qg_, const float* __restrict__ kg_,
    const int* __restrict__ mg_, float* __restrict__ ws) {
  __shared__ f16 Kl[KB * D_];
  const int tid = threadIdx.x, lane = tid & 63, wid = tid >> 6;
  const int ln = lane & 31, hi = lane >> 5;
  const int bh = blockIdx.z, b = bh >> 4;
  const int qb = blockIdx.x * QB + wid * WQ;
  const int kt0 = blockIdx.y * NKT_W;
  const float* qg = qg_ + (size_t)bh * S_ * D_;
  const float* kg = kg_ + (size_t)bh * S_ * D_;
  const int* mg = mg_ + (size_t)b * S_ * S_;
  char* KlB = (char*)Kl;

  f16x8 qf[4];
  load_qf(qg, qb + ln, hi, qf);
  float rs[16];
#pragma unroll
  for (int r = 0; r < 16; ++r) rs[r] = 0.0f;

  float4 kr[4];
  kload256(kg, kt0, tid, kr);
  for (int i = 0; i < NKT_W; ++i) {
    __syncthreads();
    kwrite256(KlB, tid, kr);
    if (i + 1 < NKT_W) kload256(kg, kt0 + i + 1, tid, kr);  // prefetch next tile
    __syncthreads();
#pragma unroll
    for (int sub = 0; sub < 2; ++sub) {
      const int t0 = (kt0 + i) * KB + sub * 32;
      const int* mrow = mg + (size_t)(qb + 4 * hi) * S_ + t0 + ln;
      int mk[16];
#pragma unroll
      for (int r = 0; r < 16; ++r) {
        const int qoff = (r & 3) + 8 * (r >> 2);
        mk[r] = mrow[(size_t)qoff * S_];
      }
      f32x16 sacc = qk8(KlB, qf, sub, ln, hi);
#pragma unroll
      for (int r = 0; r < 16; ++r) rs[r] += mk[r] ? __expf(sacc[r]) : 0.0f;
    }
  }
  float* wsrow = ws + (size_t)bh * S_;
#pragma unroll
  for (int r = 0; r < 16; ++r) {
    float s = rs[r];
    s += __shfl_xor(s, 16); s += __shfl_xor(s, 8); s += __shfl_xor(s, 4);
    s += __shfl_xor(s, 2); s += __shfl_xor(s, 1);
    if (ln == 0) {
      const int qoff = (r & 3) + 8 * (r >> 2);
      atomicAdd(wsrow + qb + qoff + 4 * hi, s);
    }
  }
}

// ---------------- K2: write normalized attn (t-split) ----------------
__global__ __launch_bounds__(256, 4) void attn_emit(
    const float* __restrict__ qg_, const float* __restrict__ kg_,
    const int* __restrict__ mg_, const float* __restrict__ ws,
    float* __restrict__ out) {
  __shared__ f16 Kl[KB * D_];
  const int tid = threadIdx.x, lane = tid & 63, wid = tid >> 6;
  const int ln = lane & 31, hi = lane >> 5;
  const int bh = blockIdx.z, b = bh >> 4;
  const int qb = blockIdx.x * QB + wid * WQ;
  const int kt0 = blockIdx.y * NKT_W;
  const float* qg = qg_ + (size_t)bh * S_ * D_;
  const float* kg = kg_ + (size_t)bh * S_ * D_;
  const int* mg = mg_ + (size_t)b * S_ * S_;
  float* attnp = out + OUT0 + (size_t)bh * S_ * S_;
  char* KlB = (char*)Kl;

  f16x8 qf[4];
  load_qf(qg, qb + ln, hi, qf);
  const float* wsrow = ws + (size_t)bh * S_;
  float rinv[16];
#pragma unroll
  for (int r = 0; r < 16; ++r) {
    const int qoff = (r & 3) + 8 * (r >> 2);
    rinv[r] = 1.0f / wsrow[qb + qoff + 4 * hi];
  }

  float4 kr[4];
  kload256(kg, kt0, tid, kr);
  for (int i = 0; i < NKT_W; ++i) {
    __syncthreads();
    kwrite256(KlB, tid, kr);
    if (i + 1 < NKT_W) kload256(kg, kt0 + i + 1, tid, kr);
    __syncthreads();
#pragma unroll
    for (int sub = 0; sub < 2; ++sub) {
      const int t0 = (kt0 + i) * KB + sub * 32;
      const int* mrow = mg + (size_t)(qb + 4 * hi) * S_ + t0 + ln;
      int mk[16];
#pragma unroll
      for (int r = 0; r < 16; ++r) {
        const int qoff = (r & 3) + 8 * (r >> 2);
        mk[r] = mrow[(size_t)qoff * S_];
      }
      f32x16 sacc = qk8(KlB, qf, sub, ln, hi);
      float* arow = attnp + (size_t)(qb + 4 * hi) * S_ + t0 + ln;
#pragma unroll
      for (int r = 0; r < 16; ++r) {
        const int qoff = (r & 3) + 8 * (r >> 2);
        float p = mk[r] ? __expf(sacc[r]) * rinv[r] : 0.0f;
        arow[(size_t)qoff * S_] = p;
      }
    }
  }
}

// ---------------- K3: out = P@V + v ----------------
__global__ __launch_bounds__(256) void attn_out(
    const float* __restrict__ qg_, const float* __restrict__ kg_,
    const float* __restrict__ vg_, const int* __restrict__ mg_,
    const float* __restrict__ ws, float* __restrict__ out) {
  __shared__ f16 Kl[KB * D_];
  __shared__ f16 Vt[D_ * KB];
  __shared__ f16 Pl[4 * WQ * KB];
  const int tid = threadIdx.x, lane = tid & 63, wid = tid >> 6;
  const int ln = lane & 31, hi = lane >> 5;
  const int bh = blockIdx.y, b = bh >> 4;
  const int qb = blockIdx.x * QB + wid * WQ;
  const float* qg = qg_ + (size_t)bh * S_ * D_;
  const float* kg = kg_ + (size_t)bh * S_ * D_;
  const float* vg = vg_ + (size_t)bh * S_ * D_;
  const int* mg = mg_ + (size_t)b * S_ * S_;
  float* outp = out + (size_t)bh * S_ * D_;
  char* KlB = (char*)Kl;
  char* VtB = (char*)Vt;
  char* PlB = (char*)Pl + wid * (WQ * KB * 2);

  f16x8 qf[4];
  load_qf(qg, qb + ln, hi, qf);
  const float* wsrow = ws + (size_t)bh * S_;
  float rinv[16];
#pragma unroll
  for (int r = 0; r < 16; ++r) {
    const int qoff = (r & 3) + 8 * (r >> 2);
    rinv[r] = 1.0f / wsrow[qb + qoff + 4 * hi];
  }

  f32x16 oacc0, oacc1;
#pragma unroll
  for (int i = 0; i < 16; ++i) { oacc0[i] = 0.0f; oacc1[i] = 0.0f; }

  float4 kr[4], vr[4];
  kload256(kg, 0, tid, kr);
  kload256(vg, 0, tid, vr);
  for (int kt = 0; kt < NKT; ++kt) {
    __syncthreads();
    kwrite256(KlB, tid, kr);
    vwrite256(VtB, tid, vr);
    if (kt + 1 < NKT) {  // prefetch next K+V tiles during compute
      kload256(kg, kt + 1, tid, kr);
      kload256(vg, kt + 1, tid, vr);
    }
    __syncthreads();
#pragma unroll
    for (int sub = 0; sub < 2; ++sub) {
      const int t0 = kt * KB + sub * 32;
      const int* mrow = mg + (size_t)(qb + 4 * hi) * S_ + t0 + ln;
      int mk[16];
#pragma unroll
      for (int r = 0; r < 16; ++r) {
        const int qoff = (r & 3) + 8 * (r >> 2);
        mk[r] = mrow[(size_t)qoff * S_];
      }
      f32x16 sacc = qk8(KlB, qf, sub, ln, hi);
#pragma unroll
      for (int r = 0; r < 16; ++r) {
        const int qoff = (r & 3) + 8 * (r >> 2);
        float p = mk[r] ? __expf(sacc[r]) * rinv[r] : 0.0f;
        *(f16*)(PlB + swzb(qoff + 4 * hi, sub * 32 + ln)) = (f16)p;
      }
    }
#pragma unroll
    for (int ts = 0; ts < 4; ++ts) {
      f16x8 pa = *(const f16x8*)(PlB + swzb(ln, ts * 16 + hi * 8));
      f16x8 vb0 = *(const f16x8*)(VtB + swzb(ln, ts * 16 + hi * 8));
      f16x8 vb1 = *(const f16x8*)(VtB + swzb(32 + ln, ts * 16 + hi * 8));
      oacc0 = MFMA16(pa, vb0, oacc0);
      oacc1 = MFMA16(pa, vb1, oacc1);
    }
  }

#pragma unroll
  for (int r = 0; r < 16; ++r) {
    const int qoff = (r & 3) + 8 * (r >> 2);
    const size_t o = (size_t)(qb + qoff + 4 * hi) * D_ + ln;
    outp[o] = oacc0[r] + vg[o];
    outp[o + 32] = oacc1[r] + vg[o + 32];
  }
}

extern "C" void kernel_launch(void* const* d_in, const int* in_sizes, int n_in,
                              void* d_out, int out_size, void* d_ws, size_t ws_size,
                              hipStream_t stream) {
  (void)in_sizes; (void)n_in; (void)out_size; (void)ws_size;
  const float* q = (const float*)d_in[0];
  const float* k = (const float*)d_in[1];
  const float* v = (const float*)d_in[2];
  const int* mask = (const int*)d_in[3];
  float* out = (float*)d_out;
  float* wsf = (float*)d_ws;  // rsum: [BH][S] f32 = 512 KB

  const int nsum = BH * S_;
  zero_ws<<<dim3((nsum + 255) / 256), dim3(256), 0, stream>>>(wsf, nsum);
  attn_rsum<<<dim3(S_ / QB, NSPLIT, BH), dim3(256), 0, stream>>>(q, k, mask, wsf);
  attn_emit<<<dim3(S_ / QB, NSPLIT, BH), dim3(256), 0, stream>>>(q, k, mask, wsf, out);
  attn_out<<<dim3(S_ / QB, BH), dim3(256), 0, stream>>>(q, k, v, mask, wsf, out);
}

// Round 8
// 1937.094 us; speedup vs baseline: 1.1365x; 1.1120x over previous
//
#include <hip/hip_runtime.h>

typedef _Float16 f16;
typedef _Float16 f16x4 __attribute__((ext_vector_type(4)));
typedef _Float16 f16x8 __attribute__((ext_vector_type(8)));
typedef float f32x16 __attribute__((ext_vector_type(16)));

#define MFMA16(a, b, c) __builtin_amdgcn_mfma_f32_32x32x16_f16((a), (b), (c), 0, 0, 0)

constexpr int B_ = 4, H_ = 16, S_ = 2048, D_ = 64, BH = 64;
constexpr int QB = 128;            // q rows per WG (4 waves x 32)
constexpr int WQ = 32;             // q rows per wave
constexpr int KB = 64;             // k/v rows per LDS tile
constexpr int TS = 512;            // t-range per WG for K1/K2
constexpr int NSPLIT = S_ / TS;    // 4
constexpr int NKT_W = TS / KB;     // 8
constexpr int NKT = S_ / KB;       // 32
constexpr int MW = S_ / 32;        // 64 bitmask words per row
constexpr size_t OUT0 = (size_t)B_ * H_ * S_ * D_;
// ws layout: [0, 2MB) bitmask u32[4][S][MW]; [2MB, 2.5MB) rsum f32[BH][S]
constexpr size_t WS_RSUM_OFF = (size_t)B_ * S_ * MW;  // in u32 units

__device__ __forceinline__ int swzb(int row, int col /*f16 units*/) {
  int byte = (row << 7) + (col << 1);
  return byte ^ ((row & 7) << 4);
}

__device__ __forceinline__ void kload256(const float* g, int kt, int tid, float4 kr[4]) {
#pragma unroll
  for (int rep = 0; rep < 4; ++rep) {
    int idx = (rep * 256 + tid) * 4;
    kr[rep] = *(const float4*)(g + (size_t)(kt * KB + (idx >> 6)) * D_ + (idx & 63));
  }
}
__device__ __forceinline__ void kwrite256(char* KlB, int tid, const float4 kr[4]) {
#pragma unroll
  for (int rep = 0; rep < 4; ++rep) {
    int idx = (rep * 256 + tid) * 4;
    f16x4 hx = {(f16)kr[rep].x, (f16)kr[rep].y, (f16)kr[rep].z, (f16)kr[rep].w};
    *(f16x4*)(KlB + swzb(idx >> 6, idx & 63)) = hx;
  }
}
__device__ __forceinline__ void vwrite256(char* VtB, int tid, const float4 vr[4]) {
#pragma unroll
  for (int rep = 0; rep < 4; ++rep) {
    int idx = (rep * 256 + tid) * 4;
    int row = idx >> 6, col = idx & 63;
    *(f16*)(VtB + swzb(col + 0, row)) = (f16)vr[rep].x;
    *(f16*)(VtB + swzb(col + 1, row)) = (f16)vr[rep].y;
    *(f16*)(VtB + swzb(col + 2, row)) = (f16)vr[rep].z;
    *(f16*)(VtB + swzb(col + 3, row)) = (f16)vr[rep].w;
  }
}

__device__ __forceinline__ void load_qf(const float* qg, int qrow, int hi, f16x8 qf[4]) {
  const float* qr = qg + (size_t)qrow * D_;
#pragma unroll
  for (int s = 0; s < 4; ++s) {
    const int d0 = s * 16 + hi * 8;
    float4 a = *(const float4*)(qr + d0);
    float4 c = *(const float4*)(qr + d0 + 4);
    f16x8 t;
    t[0] = (f16)(a.x * 0.125f); t[1] = (f16)(a.y * 0.125f);
    t[2] = (f16)(a.z * 0.125f); t[3] = (f16)(a.w * 0.125f);
    t[4] = (f16)(c.x * 0.125f); t[5] = (f16)(c.y * 0.125f);
    t[6] = (f16)(c.z * 0.125f); t[7] = (f16)(c.w * 0.125f);
    qf[s] = t;
  }
}

__device__ __forceinline__ f32x16 qk8(const char* KlB, const f16x8 qf[4], int sub, int ln, int hi) {
  f32x16 s;
#pragma unroll
  for (int i = 0; i < 16; ++i) s[i] = 0.0f;
#pragma unroll
  for (int t = 0; t < 4; ++t) {
    f16x8 kf = *(const f16x8*)(KlB + swzb(sub * 32 + ln, t * 16 + hi * 8));
    s = MFMA16(qf[t], kf, s);
  }
  return s;
}

// ---------------- K0: zero the rsum workspace region ----------------
__global__ void zero_ws(float* __restrict__ p, int n) {
  int i = blockIdx.x * blockDim.x + threadIdx.x;
  if (i < n) p[i] = 0.0f;
}

// ---------------- Kp: pack mask int32 -> 1 bit (67 MB -> 2 MB) ----------------
__global__ __launch_bounds__(256) void mask_pack(const int* __restrict__ mg,
                                                 unsigned* __restrict__ mb) {
  const int tid = threadIdx.x, lane = tid & 63, wid = tid >> 6;
  const int row = blockIdx.x * 4 + wid;  // [0, 4*2048): b*S + s
  const int* mrow = mg + (size_t)row * S_;
  unsigned long long myw = 0;
#pragma unroll
  for (int w = 0; w < 32; ++w) {
    int m = mrow[w * 64 + lane];
    unsigned long long bal = __ballot(m != 0);
    if (lane == w) myw = bal;
  }
  if (lane < 32) *(unsigned long long*)(mb + (size_t)row * MW + 2 * lane) = myw;
}

// ---------------- K1: masked exp row-sums (t-split, atomic) ----------------
__global__ __launch_bounds__(256, 4) void attn_rsum(
    const float* __restrict__ qg_, const float* __restrict__ kg_,
    const unsigned* __restrict__ mb, float* __restrict__ ws) {
  __shared__ f16 Kl[KB * D_];
  const int tid = threadIdx.x, lane = tid & 63, wid = tid >> 6;
  const int ln = lane & 31, hi = lane >> 5;
  // XCD-chunked decode: contiguous bh range per XCD for K/bitmask L2 reuse
  const int i = blockIdx.x;
  const int work = (i & 7) * 512 + (i >> 3);
  const int bh = work >> 6, rem = work & 63;
  const int qb = (rem & 15) * QB + wid * WQ;
  const int kt0 = (rem >> 4) * NKT_W;
  const int b = bh >> 4;
  const float* qg = qg_ + (size_t)bh * S_ * D_;
  const float* kg = kg_ + (size_t)bh * S_ * D_;
  const unsigned* mbB = mb + (size_t)b * S_ * MW;
  char* KlB = (char*)Kl;

  f16x8 qf[4];
  load_qf(qg, qb + ln, hi, qf);
  float rs[16];
#pragma unroll
  for (int r = 0; r < 16; ++r) rs[r] = 0.0f;

  float4 kr[4];
  kload256(kg, kt0, tid, kr);
  for (int it = 0; it < NKT_W; ++it) {
    __syncthreads();
    kwrite256(KlB, tid, kr);
    if (it + 1 < NKT_W) kload256(kg, kt0 + it + 1, tid, kr);
    __syncthreads();
#pragma unroll
    for (int sub = 0; sub < 2; ++sub) {
      const int t0 = (kt0 + it) * KB + sub * 32;
      f32x16 sacc = qk8(KlB, qf, sub, ln, hi);
#pragma unroll
      for (int r = 0; r < 16; ++r) {
        const int qoff = (r & 3) + 8 * (r >> 2);
        const unsigned mw = mbB[(size_t)(qb + qoff + 4 * hi) * MW + (t0 >> 5)];
        rs[r] += ((mw >> ln) & 1u) ? __expf(sacc[r]) : 0.0f;
      }
    }
  }
  float* wsrow = ws + (size_t)bh * S_;
#pragma unroll
  for (int r = 0; r < 16; ++r) {
    float s = rs[r];
    s += __shfl_xor(s, 16); s += __shfl_xor(s, 8); s += __shfl_xor(s, 4);
    s += __shfl_xor(s, 2); s += __shfl_xor(s, 1);
    if (ln == 0) {
      const int qoff = (r & 3) + 8 * (r >> 2);
      atomicAdd(wsrow + qb + qoff + 4 * hi, s);
    }
  }
}

// ---------------- K2: write normalized attn (t-split) ----------------
__global__ __launch_bounds__(256, 4) void attn_emit(
    const float* __restrict__ qg_, const float* __restrict__ kg_,
    const unsigned* __restrict__ mb, const float* __restrict__ ws,
    float* __restrict__ out) {
  __shared__ f16 Kl[KB * D_];
  const int tid = threadIdx.x, lane = tid & 63, wid = tid >> 6;
  const int ln = lane & 31, hi = lane >> 5;
  const int i = blockIdx.x;
  const int work = (i & 7) * 512 + (i >> 3);
  const int bh = work >> 6, rem = work & 63;
  const int qb = (rem & 15) * QB + wid * WQ;
  const int kt0 = (rem >> 4) * NKT_W;
  const int b = bh >> 4;
  const float* qg = qg_ + (size_t)bh * S_ * D_;
  const float* kg = kg_ + (size_t)bh * S_ * D_;
  const unsigned* mbB = mb + (size_t)b * S_ * MW;
  float* attnp = out + OUT0 + (size_t)bh * S_ * S_;
  char* KlB = (char*)Kl;

  f16x8 qf[4];
  load_qf(qg, qb + ln, hi, qf);
  const float* wsrow = ws + (size_t)bh * S_;
  float rinv[16];
#pragma unroll
  for (int r = 0; r < 16; ++r) {
    const int qoff = (r & 3) + 8 * (r >> 2);
    rinv[r] = 1.0f / wsrow[qb + qoff + 4 * hi];
  }

  float4 kr[4];
  kload256(kg, kt0, tid, kr);
  for (int it = 0; it < NKT_W; ++it) {
    __syncthreads();
    kwrite256(KlB, tid, kr);
    if (it + 1 < NKT_W) kload256(kg, kt0 + it + 1, tid, kr);
    __syncthreads();
#pragma unroll
    for (int sub = 0; sub < 2; ++sub) {
      const int t0 = (kt0 + it) * KB + sub * 32;
      f32x16 sacc = qk8(KlB, qf, sub, ln, hi);
      float* arow = attnp + (size_t)(qb + 4 * hi) * S_ + t0 + ln;
#pragma unroll
      for (int r = 0; r < 16; ++r) {
        const int qoff = (r & 3) + 8 * (r >> 2);
        const unsigned mw = mbB[(size_t)(qb + qoff + 4 * hi) * MW + (t0 >> 5)];
        float p = ((mw >> ln) & 1u) ? __expf(sacc[r]) * rinv[r] : 0.0f;
        arow[(size_t)qoff * S_] = p;
      }
    }
  }
}

// ---------------- K3: out = P@V + v ----------------
__global__ __launch_bounds__(256) void attn_out(
    const float* __restrict__ qg_, const float* __restrict__ kg_,
    const float* __restrict__ vg_, const unsigned* __restrict__ mb,
    const float* __restrict__ ws, float* __restrict__ out) {
  __shared__ f16 Kl[KB * D_];
  __shared__ f16 Vt[D_ * KB];
  __shared__ f16 Pl[4 * WQ * KB];
  const int tid = threadIdx.x, lane = tid & 63, wid = tid >> 6;
  const int ln = lane & 31, hi = lane >> 5;
  const int i = blockIdx.x;
  const int work = (i & 7) * 128 + (i >> 3);
  const int bh = work >> 4;
  const int qb = (work & 15) * QB + wid * WQ;
  const int b = bh >> 4;
  const float* qg = qg_ + (size_t)bh * S_ * D_;
  const float* kg = kg_ + (size_t)bh * S_ * D_;
  const float* vg = vg_ + (size_t)bh * S_ * D_;
  const unsigned* mbB = mb + (size_t)b * S_ * MW;
  float* outp = out + (size_t)bh * S_ * D_;
  char* KlB = (char*)Kl;
  char* VtB = (char*)Vt;
  char* PlB = (char*)Pl + wid * (WQ * KB * 2);

  f16x8 qf[4];
  load_qf(qg, qb + ln, hi, qf);
  const float* wsrow = ws + (size_t)bh * S_;
  float rinv[16];
#pragma unroll
  for (int r = 0; r < 16; ++r) {
    const int qoff = (r & 3) + 8 * (r >> 2);
    rinv[r] = 1.0f / wsrow[qb + qoff + 4 * hi];
  }

  f32x16 oacc0, oacc1;
#pragma unroll
  for (int i2 = 0; i2 < 16; ++i2) { oacc0[i2] = 0.0f; oacc1[i2] = 0.0f; }

  float4 kr[4], vr[4];
  kload256(kg, 0, tid, kr);
  kload256(vg, 0, tid, vr);
  for (int kt = 0; kt < NKT; ++kt) {
    __syncthreads();
    kwrite256(KlB, tid, kr);
    vwrite256(VtB, tid, vr);
    if (kt + 1 < NKT) {
      kload256(kg, kt + 1, tid, kr);
      kload256(vg, kt + 1, tid, vr);
    }
    __syncthreads();
#pragma unroll
    for (int sub = 0; sub < 2; ++sub) {
      const int t0 = kt * KB + sub * 32;
      f32x16 sacc = qk8(KlB, qf, sub, ln, hi);
#pragma unroll
      for (int r = 0; r < 16; ++r) {
        const int qoff = (r & 3) + 8 * (r >> 2);
        const unsigned mw = mbB[(size_t)(qb + qoff + 4 * hi) * MW + (t0 >> 5)];
        float p = ((mw >> ln) & 1u) ? __expf(sacc[r]) * rinv[r] : 0.0f;
        *(f16*)(PlB + swzb(qoff + 4 * hi, sub * 32 + ln)) = (f16)p;
      }
    }
#pragma unroll
    for (int ts = 0; ts < 4; ++ts) {
      f16x8 pa = *(const f16x8*)(PlB + swzb(ln, ts * 16 + hi * 8));
      f16x8 vb0 = *(const f16x8*)(VtB + swzb(ln, ts * 16 + hi * 8));
      f16x8 vb1 = *(const f16x8*)(VtB + swzb(32 + ln, ts * 16 + hi * 8));
      oacc0 = MFMA16(pa, vb0, oacc0);
      oacc1 = MFMA16(pa, vb1, oacc1);
    }
  }

#pragma unroll
  for (int r = 0; r < 16; ++r) {
    const int qoff = (r & 3) + 8 * (r >> 2);
    const size_t o = (size_t)(qb + qoff + 4 * hi) * D_ + ln;
    outp[o] = oacc0[r] + vg[o];
    outp[o + 32] = oacc1[r] + vg[o + 32];
  }
}

extern "C" void kernel_launch(void* const* d_in, const int* in_sizes, int n_in,
                              void* d_out, int out_size, void* d_ws, size_t ws_size,
                              hipStream_t stream) {
  (void)in_sizes; (void)n_in; (void)out_size; (void)ws_size;
  const float* q = (const float*)d_in[0];
  const float* k = (const float*)d_in[1];
  const float* v = (const float*)d_in[2];
  const int* mask = (const int*)d_in[3];
  float* out = (float*)d_out;
  unsigned* mb = (unsigned*)d_ws;                 // 2 MB bitmask
  float* rs = (float*)d_ws + WS_RSUM_OFF;         // 512 KB row sums

  const int nsum = BH * S_;
  zero_ws<<<dim3((nsum + 255) / 256), dim3(256), 0, stream>>>(rs, nsum);
  mask_pack<<<dim3(B_ * S_ / 4), dim3(256), 0, stream>>>(mask, mb);
  attn_rsum<<<dim3(16 * NSPLIT * BH), dim3(256), 0, stream>>>(q, k, mb, rs);
  attn_emit<<<dim3(16 * NSPLIT * BH), dim3(256), 0, stream>>>(q, k, mb, rs, out);
  attn_out<<<dim3(16 * BH), dim3(256), 0, stream>>>(q, k, v, mb, rs, out);
}